// Round 2
// baseline (386.177 us; speedup 1.0000x reference)
//
#include <hip/hip_runtime.h>
#include <stdint.h>

#define E_TOTAL 100000
#define B_TOTAL 8
#define CIN 32
#define COUT 64
#define TILES 1563   // ceil(E_TOTAL/64) for transpose
#define NUNITS 782   // ceil(E_TOTAL/128): 128-e units for main (block covers 4 waves x 32 e)
#define NBLK 256     // blocks per batch in main (grid = 8*NBLK)

typedef float f32x4  __attribute__((ext_vector_type(4)));
typedef int   i32x4  __attribute__((ext_vector_type(4)));
typedef unsigned u32x4 __attribute__((ext_vector_type(4)));
typedef _Float16 h16x8 __attribute__((ext_vector_type(8)));

union HU { u32x4 u; h16x8 h; };

// fp32 pair -> packed fp16 pair (single v_cvt_pkrtz_f16_f32)
__device__ inline unsigned pkh(float lo, float hi) {
    auto r = __builtin_amdgcn_cvt_pkrtz(lo, hi);   // __fp16 ext_vector(2)
    return __builtin_bit_cast(unsigned, r);
}
__device__ inline h16x8 ash(u32x4 v) { HU x; x.u = v; return x.h; }
// |a - b| : 4x v_pk_sub_f16 + 4x v_and_b32
__device__ inline h16x8 habsd(h16x8 a, h16x8 b) {
    HU x; x.h = a - b;
#pragma unroll
    for (int i = 0; i < 4; i++) x.u[i] &= 0x7fff7fffu;
    return x.h;
}

// ---- kernel 1: fused weight-prep + x transpose/cast (fp16) ----
__global__ __launch_bounds__(256) void prep_transpose(
    const float* __restrict__ x, unsigned* __restrict__ xt,
    const float* __restrict__ w, unsigned short* __restrict__ wb) {
    const int tid = threadIdx.x;
    if (blockIdx.x >= TILES * 8) {
        for (int idx = tid; idx < 4 * 5 * 64 * 8; idx += 256) {
            int j = idx & 7;
            int lane = (idx >> 3) & 63;
            int tg = idx >> 9;
            int g = tg % 5;
            int t = tg / 5;
            int nn = lane & 15, qq = lane >> 4;
            int o = nn + 16 * t;
            int c = qq * 8 + j;
            _Float16 hv = (_Float16)w[(o * CIN + c) * 5 + g];   // RNE fp32->fp16
            wb[idx] = __builtin_bit_cast(unsigned short, hv);
        }
        return;
    }
    __shared__ float tbuf[CIN][65];
    const int b = blockIdx.x & 7;            // batch -> XCD affinity
    const int e0 = (blockIdx.x >> 3) * 64;
    const int el = tid & 63;
    const int cw = tid >> 6;
#pragma unroll
    for (int i = 0; i < 8; i++) {
        int c = cw * 8 + i;
        int e = e0 + el;
        float v = (e < E_TOTAL)
            ? __builtin_nontemporal_load(x + ((size_t)b * CIN + c) * E_TOTAL + e)
            : 0.f;
        tbuf[c][el] = v;
    }
    __syncthreads();
    const int c2 = tid & 15;
#pragma unroll
    for (int i = 0; i < 4; i++) {
        int el2 = (tid >> 4) * 4 + i;
        int e = e0 + el2;
        if (e < E_TOTAL) {
            xt[((size_t)b * E_TOTAL + e) * 16 + c2] =
                pkh(tbuf[c2 * 2][el2], tbuf[c2 * 2 + 1][el2]);
        }
    }
}

// ---- kernel 2: gather + symmetric functions + MFMA GEMM (fp16, pipelined) ----
// Consume-then-issue pipeline: the 8 random row-gathers for unit u are issued
// in iteration u-1, so their L2/L3 latency hides under that iteration's
// 40 MFMAs + stores instead of stalling at a waitcnt.
__global__ __launch_bounds__(256) void meshconv_main(
    const unsigned short* __restrict__ xt,   // (B,E,32) fp16
    const int* __restrict__ ge,              // (B,E,4)
    const u32x4* __restrict__ wb,            // frag-ready fp16 weights (20 KB)
    const float* __restrict__ bias,          // (64)
    float* __restrict__ out) {               // (B,64,E) fp32
    __shared__ u32x4 wlds[1280];
    const int tid = threadIdx.x;
    const int lane = tid & 63;
    const int wv = tid >> 6;
    const int b = blockIdx.x & 7;            // batch -> XCD affinity
    const int blk = blockIdx.x >> 3;
    const int n = lane & 15;
    const int q = lane >> 4;
    const int co = q * 8;

#pragma unroll
    for (int k = 0; k < 5; k++) wlds[tid + k * 256] = wb[tid + k * 256];
    __syncthreads();

    const unsigned short* xb = xt + (size_t)b * E_TOTAL * CIN;
    const int* geb = ge + (size_t)b * E_TOTAL * 4;
    float bv[4];
#pragma unroll
    for (int t = 0; t < 4; t++) bv[t] = bias[n + 16 * t];

    // ---- pipeline prologue ----
    int u = blk;
    int e0 = u * 128 + wv * 32;
    bool act = (u < NUNITS) && (e0 < E_TOTAL);   // E%32==0: full waves only
    i32x4 nidA0, nidA1;
    u32x4 sA0, sA1;
    if (act) {
        nidA0 = __builtin_nontemporal_load((const i32x4*)(geb + (size_t)(e0 + n) * 4));
        nidA1 = __builtin_nontemporal_load((const i32x4*)(geb + (size_t)(e0 + 16 + n) * 4));
        sA0 = *(const u32x4*)(xb + (size_t)(e0 + n) * CIN + co);
        sA1 = *(const u32x4*)(xb + (size_t)(e0 + 16 + n) * CIN + co);
    }
    // issue unit u's gathers now (prologue pays this latency once)
    u32x4 g10, g20, g30, g40, g11, g21, g31, g41;
    if (act) {
        g10 = *(const u32x4*)(xb + (size_t)nidA0[0] * CIN + co);
        g20 = *(const u32x4*)(xb + (size_t)nidA0[1] * CIN + co);
        g30 = *(const u32x4*)(xb + (size_t)nidA0[2] * CIN + co);
        g40 = *(const u32x4*)(xb + (size_t)nidA0[3] * CIN + co);
        g11 = *(const u32x4*)(xb + (size_t)nidA1[0] * CIN + co);
        g21 = *(const u32x4*)(xb + (size_t)nidA1[1] * CIN + co);
        g31 = *(const u32x4*)(xb + (size_t)nidA1[2] * CIN + co);
        g41 = *(const u32x4*)(xb + (size_t)nidA1[3] * CIN + co);
    }
    // prefetch unit u+NBLK indices + self rows
    int un = u + NBLK;
    int e0n = un * 128 + wv * 32;
    bool actn = (un < NUNITS) && (e0n < E_TOTAL);
    i32x4 nidB0, nidB1;
    u32x4 sB0, sB1;
    if (actn) {
        nidB0 = __builtin_nontemporal_load((const i32x4*)(geb + (size_t)(e0n + n) * 4));
        nidB1 = __builtin_nontemporal_load((const i32x4*)(geb + (size_t)(e0n + 16 + n) * 4));
        sB0 = *(const u32x4*)(xb + (size_t)(e0n + n) * CIN + co);
        sB1 = *(const u32x4*)(xb + (size_t)(e0n + 16 + n) * CIN + co);
    }

    for (; u < NUNITS; u += NBLK) {
        const int e0c = u * 128 + wv * 32;

        // symmetric functions: consumes this unit's gathers (issued last iter)
        h16x8 A0[5], A1[5];
        if (act) {
            A0[0] = ash(sA0);
            A0[1] = ash(g10) + ash(g30);
            A0[2] = ash(g20) + ash(g40);
            A0[3] = habsd(ash(g10), ash(g30));
            A0[4] = habsd(ash(g20), ash(g40));
            A1[0] = ash(sA1);
            A1[1] = ash(g11) + ash(g31);
            A1[2] = ash(g21) + ash(g41);
            A1[3] = habsd(ash(g11), ash(g31));
            A1[4] = habsd(ash(g21), ash(g41));
        }

        // g registers now dead -> issue NEXT unit's 8 gathers into them
        if (actn) {
            g10 = *(const u32x4*)(xb + (size_t)nidB0[0] * CIN + co);
            g20 = *(const u32x4*)(xb + (size_t)nidB0[1] * CIN + co);
            g30 = *(const u32x4*)(xb + (size_t)nidB0[2] * CIN + co);
            g40 = *(const u32x4*)(xb + (size_t)nidB0[3] * CIN + co);
            g11 = *(const u32x4*)(xb + (size_t)nidB1[0] * CIN + co);
            g21 = *(const u32x4*)(xb + (size_t)nidB1[1] * CIN + co);
            g31 = *(const u32x4*)(xb + (size_t)nidB1[2] * CIN + co);
            g41 = *(const u32x4*)(xb + (size_t)nidB1[3] * CIN + co);
        }

        // rotate self rows; prefetch unit u+2*NBLK indices + self
        u32x4 sN0 = sB0, sN1 = sB1;
        const int u2 = u + 2 * NBLK;
        const int e02 = u2 * 128 + wv * 32;
        const bool act2 = (u2 < NUNITS) && (e02 < E_TOTAL);
        if (act2) {
            nidB0 = __builtin_nontemporal_load((const i32x4*)(geb + (size_t)(e02 + n) * 4));
            nidB1 = __builtin_nontemporal_load((const i32x4*)(geb + (size_t)(e02 + 16 + n) * 4));
            sB0 = *(const u32x4*)(xb + (size_t)(e02 + n) * CIN + co);
            sB1 = *(const u32x4*)(xb + (size_t)(e02 + 16 + n) * CIN + co);
        }

        if (act) {
            // accumulators pre-loaded with bias (saves epilogue adds)
            f32x4 acc0[4], acc1[4];
#pragma unroll
            for (int t = 0; t < 4; t++)
#pragma unroll
                for (int r = 0; r < 4; r++) { acc0[t][r] = bv[t]; acc1[t][r] = bv[t]; }

#pragma unroll
            for (int g = 0; g < 5; g++) {
#pragma unroll
                for (int t = 0; t < 4; t++) {
                    HU bw; bw.u = wlds[(t * 5 + g) * 64 + lane];
                    acc0[t] = __builtin_amdgcn_mfma_f32_16x16x32_f16(A0[g], bw.h, acc0[t], 0, 0, 0);
                    acc1[t] = __builtin_amdgcn_mfma_f32_16x16x32_f16(A1[g], bw.h, acc1[t], 0, 0, 0);
                }
            }

            // per o-row: two adjacent f32x4 stores -> 128 B contiguous per wave
#pragma unroll
            for (int t = 0; t < 4; t++) {
                const int o = n + 16 * t;
                float* orow = out + ((size_t)b * COUT + o) * E_TOTAL + e0c + q * 4;
                __builtin_nontemporal_store(acc0[t], (f32x4*)orow);
                __builtin_nontemporal_store(acc1[t], (f32x4*)(orow + 16));
            }
        }

        sA0 = sN0; sA1 = sN1;
        act = actn; actn = act2;
    }
}

// ---- fallback (insufficient scratch): direct fp32, slow but correct ----
__global__ __launch_bounds__(256) void meshconv_fallback(
    const float* __restrict__ x, const int* __restrict__ ge,
    const float* __restrict__ w, const float* __restrict__ bias,
    float* __restrict__ out) {
    __shared__ float f[5][32];
    __shared__ float G[5][32];
    __shared__ int idxs[4];
    const int e = blockIdx.x, b = blockIdx.y;
    const int tid = threadIdx.x;
    if (tid < 4) idxs[tid] = ge[((size_t)b * E_TOTAL + e) * 4 + tid];
    __syncthreads();
    if (tid < 160) {
        int k = tid >> 5, c = tid & 31;
        int src = (k == 0) ? e : idxs[k - 1];
        f[k][c] = x[((size_t)b * CIN + c) * E_TOTAL + src];
    }
    __syncthreads();
    if (tid < 32) {
        int c = tid;
        G[0][c] = f[0][c];
        G[1][c] = f[1][c] + f[3][c];
        G[2][c] = f[2][c] + f[4][c];
        G[3][c] = fabsf(f[1][c] - f[3][c]);
        G[4][c] = fabsf(f[2][c] - f[4][c]);
    }
    __syncthreads();
    if (tid < COUT) {
        float acc = bias[tid];
        for (int c = 0; c < CIN; c++)
#pragma unroll
            for (int g = 0; g < 5; g++)
                acc += G[g][c] * w[(tid * CIN + c) * 5 + g];
        out[((size_t)b * COUT + tid) * E_TOTAL + e] = acc;
    }
}

extern "C" void kernel_launch(void* const* d_in, const int* in_sizes, int n_in,
                              void* d_out, int out_size, void* d_ws, size_t ws_size,
                              hipStream_t stream) {
    const float* x = (const float*)d_in[0];
    const int* ge = (const int*)d_in[1];
    const float* w = (const float*)d_in[2];
    const float* bias = (const float*)d_in[3];
    float* out = (float*)d_out;

    const size_t xt_bytes = (size_t)B_TOTAL * E_TOTAL * CIN * 2;  // 51.2 MB
    const size_t need = 65536 + xt_bytes;
    if (ws_size < need) {
        dim3 grid(E_TOTAL, B_TOTAL);
        meshconv_fallback<<<grid, 256, 0, stream>>>(x, ge, w, bias, out);
        return;
    }
    unsigned short* wb = (unsigned short*)d_ws;
    unsigned short* xt = (unsigned short*)((char*)d_ws + 65536);

    prep_transpose<<<TILES * 8 + 1, 256, 0, stream>>>(x, (unsigned*)xt, w, wb);
    meshconv_main<<<NBLK * 8, 256, 0, stream>>>(xt, ge, (const u32x4*)wb, bias, out);
}

// Round 3
// 374.970 us; speedup vs baseline: 1.0299x; 1.0299x over previous
//
#include <hip/hip_runtime.h>
#include <stdint.h>

#define E_TOTAL 100000
#define B_TOTAL 8
#define CIN 32
#define COUT 64
#define TILES 1563   // ceil(E_TOTAL/64) for transpose
#define NUNITS 782   // ceil(E_TOTAL/128): 128-e units for main (block covers 4 waves x 32 e)
#define NBLK 256     // blocks per batch in main (grid = 8*NBLK)

typedef float f32x4  __attribute__((ext_vector_type(4)));
typedef int   i32x4  __attribute__((ext_vector_type(4)));
typedef unsigned u32x4 __attribute__((ext_vector_type(4)));
typedef _Float16 h16x8 __attribute__((ext_vector_type(8)));

union HU { u32x4 u; h16x8 h; };

// fp32 pair -> packed fp16 pair (single v_cvt_pkrtz_f16_f32)
__device__ inline unsigned pkh(float lo, float hi) {
    auto r = __builtin_amdgcn_cvt_pkrtz(lo, hi);   // __fp16 ext_vector(2)
    return __builtin_bit_cast(unsigned, r);
}
__device__ inline h16x8 ash(u32x4 v) { HU x; x.u = v; return x.h; }
// |a - b| : 4x v_pk_sub_f16 + 4x v_and_b32
__device__ inline h16x8 habsd(h16x8 a, h16x8 b) {
    HU x; x.h = a - b;
#pragma unroll
    for (int i = 0; i < 4; i++) x.u[i] &= 0x7fff7fffu;
    return x.h;
}

// ---- kernel 1: fused weight-prep + x transpose/cast (fp16) ----
__global__ __launch_bounds__(256) void prep_transpose(
    const float* __restrict__ x, unsigned* __restrict__ xt,
    const float* __restrict__ w, unsigned short* __restrict__ wb) {
    const int tid = threadIdx.x;
    if (blockIdx.x >= TILES * 8) {
        for (int idx = tid; idx < 4 * 5 * 64 * 8; idx += 256) {
            int j = idx & 7;
            int lane = (idx >> 3) & 63;
            int tg = idx >> 9;
            int g = tg % 5;
            int t = tg / 5;
            int nn = lane & 15, qq = lane >> 4;
            int o = nn + 16 * t;
            int c = qq * 8 + j;
            _Float16 hv = (_Float16)w[(o * CIN + c) * 5 + g];   // RNE fp32->fp16
            wb[idx] = __builtin_bit_cast(unsigned short, hv);
        }
        return;
    }
    __shared__ float tbuf[CIN][65];
    const int b = blockIdx.x & 7;            // batch -> XCD affinity
    const int e0 = (blockIdx.x >> 3) * 64;
    const int el = tid & 63;
    const int cw = tid >> 6;
#pragma unroll
    for (int i = 0; i < 8; i++) {
        int c = cw * 8 + i;
        int e = e0 + el;
        float v = (e < E_TOTAL)
            ? __builtin_nontemporal_load(x + ((size_t)b * CIN + c) * E_TOTAL + e)
            : 0.f;
        tbuf[c][el] = v;
    }
    __syncthreads();
    const int c2 = tid & 15;
#pragma unroll
    for (int i = 0; i < 4; i++) {
        int el2 = (tid >> 4) * 4 + i;
        int e = e0 + el2;
        if (e < E_TOTAL) {
            xt[((size_t)b * E_TOTAL + e) * 16 + c2] =
                pkh(tbuf[c2 * 2][el2], tbuf[c2 * 2 + 1][el2]);
        }
    }
}

// ---- kernel 2: gather + symmetric functions + MFMA GEMM ----
// Register-lean pipeline: no long-lived A arrays; each symmetric pair (g1,g3)
// / (g2,g4) is consumed into transient MFMA operands, its 16 MFMAs run, and
// the 4 gather slots are immediately re-issued for the next unit. Peak live
// state ~130 VGPR -> target 4 waves/SIMD for latency hiding.
__global__ __launch_bounds__(256) void meshconv_main(
    const unsigned short* __restrict__ xt,   // (B,E,32) fp16
    const int* __restrict__ ge,              // (B,E,4)
    const u32x4* __restrict__ wb,            // frag-ready fp16 weights (20 KB)
    const float* __restrict__ bias,          // (64)
    float* __restrict__ out) {               // (B,64,E) fp32
    __shared__ u32x4 wlds[1280];
    const int tid = threadIdx.x;
    const int lane = tid & 63;
    const int wv = tid >> 6;
    const int b = blockIdx.x & 7;            // batch -> XCD affinity
    const int blk = blockIdx.x >> 3;
    const int n = lane & 15;
    const int q = lane >> 4;
    const int co = q * 8;

#pragma unroll
    for (int k = 0; k < 5; k++) wlds[tid + k * 256] = wb[tid + k * 256];
    __syncthreads();

    const unsigned short* xb = xt + (size_t)b * E_TOTAL * CIN;
    const int* geb = ge + (size_t)b * E_TOTAL * 4;
    float bv[4];
#pragma unroll
    for (int t = 0; t < 4; t++) bv[t] = bias[n + 16 * t];

    // ---- pipeline prologue ----
    int u = blk;
    int e0 = u * 128 + wv * 32;
    bool act = (u < NUNITS) && (e0 < E_TOTAL);   // E%32==0: full waves only
    i32x4 nidA0, nidA1;
    u32x4 sA0, sA1;
    if (act) {
        nidA0 = __builtin_nontemporal_load((const i32x4*)(geb + (size_t)(e0 + n) * 4));
        nidA1 = __builtin_nontemporal_load((const i32x4*)(geb + (size_t)(e0 + 16 + n) * 4));
        sA0 = *(const u32x4*)(xb + (size_t)(e0 + n) * CIN + co);
        sA1 = *(const u32x4*)(xb + (size_t)(e0 + 16 + n) * CIN + co);
    }
    // issue unit u's gathers now (prologue pays this latency once)
    u32x4 g10, g20, g30, g40, g11, g21, g31, g41;
    if (act) {
        g10 = *(const u32x4*)(xb + (size_t)nidA0[0] * CIN + co);
        g20 = *(const u32x4*)(xb + (size_t)nidA0[1] * CIN + co);
        g30 = *(const u32x4*)(xb + (size_t)nidA0[2] * CIN + co);
        g40 = *(const u32x4*)(xb + (size_t)nidA0[3] * CIN + co);
        g11 = *(const u32x4*)(xb + (size_t)nidA1[0] * CIN + co);
        g21 = *(const u32x4*)(xb + (size_t)nidA1[1] * CIN + co);
        g31 = *(const u32x4*)(xb + (size_t)nidA1[2] * CIN + co);
        g41 = *(const u32x4*)(xb + (size_t)nidA1[3] * CIN + co);
    }
    // prefetch unit u+NBLK indices + self rows
    int un = u + NBLK;
    int e0n = un * 128 + wv * 32;
    bool actn = (un < NUNITS) && (e0n < E_TOTAL);
    i32x4 nidB0, nidB1;
    u32x4 sB0, sB1;
    if (actn) {
        nidB0 = __builtin_nontemporal_load((const i32x4*)(geb + (size_t)(e0n + n) * 4));
        nidB1 = __builtin_nontemporal_load((const i32x4*)(geb + (size_t)(e0n + 16 + n) * 4));
        sB0 = *(const u32x4*)(xb + (size_t)(e0n + n) * CIN + co);
        sB1 = *(const u32x4*)(xb + (size_t)(e0n + 16 + n) * CIN + co);
    }

    for (; u < NUNITS; u += NBLK) {
        const int e0c = u * 128 + wv * 32;

        f32x4 acc0[4], acc1[4];
#pragma unroll
        for (int t = 0; t < 4; t++)
#pragma unroll
            for (int r = 0; r < 4; r++) { acc0[t][r] = bv[t]; acc1[t][r] = bv[t]; }

        if (act) {
            // ---- g = 0 (self rows) ----
            {
                HU av0; av0.u = sA0;
                HU av1; av1.u = sA1;
#pragma unroll
                for (int t = 0; t < 4; t++) {
                    HU bw; bw.u = wlds[(t * 5 + 0) * 64 + lane];
                    acc0[t] = __builtin_amdgcn_mfma_f32_16x16x32_f16(av0.h, bw.h, acc0[t], 0, 0, 0);
                    acc1[t] = __builtin_amdgcn_mfma_f32_16x16x32_f16(av1.h, bw.h, acc1[t], 0, 0, 0);
                }
            }
            // ---- pair (g1, g3): sum + absdiff of neighbors 1,3 ----
            {
                h16x8 p0 = ash(g10) + ash(g30);
                h16x8 p1 = ash(g11) + ash(g31);
                h16x8 m0 = habsd(ash(g10), ash(g30));
                h16x8 m1 = habsd(ash(g11), ash(g31));
#pragma unroll
                for (int t = 0; t < 4; t++) {
                    HU bw; bw.u = wlds[(t * 5 + 1) * 64 + lane];
                    acc0[t] = __builtin_amdgcn_mfma_f32_16x16x32_f16(p0, bw.h, acc0[t], 0, 0, 0);
                    acc1[t] = __builtin_amdgcn_mfma_f32_16x16x32_f16(p1, bw.h, acc1[t], 0, 0, 0);
                }
#pragma unroll
                for (int t = 0; t < 4; t++) {
                    HU bw; bw.u = wlds[(t * 5 + 3) * 64 + lane];
                    acc0[t] = __builtin_amdgcn_mfma_f32_16x16x32_f16(m0, bw.h, acc0[t], 0, 0, 0);
                    acc1[t] = __builtin_amdgcn_mfma_f32_16x16x32_f16(m1, bw.h, acc1[t], 0, 0, 0);
                }
            }
        }
        // slots (1,3) dead -> re-issue for next unit
        if (actn) {
            g10 = *(const u32x4*)(xb + (size_t)nidB0[0] * CIN + co);
            g30 = *(const u32x4*)(xb + (size_t)nidB0[2] * CIN + co);
            g11 = *(const u32x4*)(xb + (size_t)nidB1[0] * CIN + co);
            g31 = *(const u32x4*)(xb + (size_t)nidB1[2] * CIN + co);
        }
        if (act) {
            // ---- pair (g2, g4): sum + absdiff of neighbors 2,4 ----
            {
                h16x8 p0 = ash(g20) + ash(g40);
                h16x8 p1 = ash(g21) + ash(g41);
                h16x8 m0 = habsd(ash(g20), ash(g40));
                h16x8 m1 = habsd(ash(g21), ash(g41));
#pragma unroll
                for (int t = 0; t < 4; t++) {
                    HU bw; bw.u = wlds[(t * 5 + 2) * 64 + lane];
                    acc0[t] = __builtin_amdgcn_mfma_f32_16x16x32_f16(p0, bw.h, acc0[t], 0, 0, 0);
                    acc1[t] = __builtin_amdgcn_mfma_f32_16x16x32_f16(p1, bw.h, acc1[t], 0, 0, 0);
                }
#pragma unroll
                for (int t = 0; t < 4; t++) {
                    HU bw; bw.u = wlds[(t * 5 + 4) * 64 + lane];
                    acc0[t] = __builtin_amdgcn_mfma_f32_16x16x32_f16(m0, bw.h, acc0[t], 0, 0, 0);
                    acc1[t] = __builtin_amdgcn_mfma_f32_16x16x32_f16(m1, bw.h, acc1[t], 0, 0, 0);
                }
            }
        }
        // slots (2,4) dead -> re-issue for next unit
        if (actn) {
            g20 = *(const u32x4*)(xb + (size_t)nidB0[1] * CIN + co);
            g40 = *(const u32x4*)(xb + (size_t)nidB0[3] * CIN + co);
            g21 = *(const u32x4*)(xb + (size_t)nidB1[1] * CIN + co);
            g41 = *(const u32x4*)(xb + (size_t)nidB1[3] * CIN + co);
        }

        // rotate self rows; prefetch unit u+2*NBLK indices + self
        u32x4 sN0 = sB0, sN1 = sB1;
        const int u2 = u + 2 * NBLK;
        const int e02 = u2 * 128 + wv * 32;
        const bool act2 = (u2 < NUNITS) && (e02 < E_TOTAL);
        if (act2) {
            nidB0 = __builtin_nontemporal_load((const i32x4*)(geb + (size_t)(e02 + n) * 4));
            nidB1 = __builtin_nontemporal_load((const i32x4*)(geb + (size_t)(e02 + 16 + n) * 4));
            sB0 = *(const u32x4*)(xb + (size_t)(e02 + n) * CIN + co);
            sB1 = *(const u32x4*)(xb + (size_t)(e02 + 16 + n) * CIN + co);
        }

        if (act) {
            // per o-row: two adjacent f32x4 stores -> 128 B contiguous per wave
#pragma unroll
            for (int t = 0; t < 4; t++) {
                const int o = n + 16 * t;
                float* orow = out + ((size_t)b * COUT + o) * E_TOTAL + e0c + q * 4;
                __builtin_nontemporal_store(acc0[t], (f32x4*)orow);
                __builtin_nontemporal_store(acc1[t], (f32x4*)(orow + 16));
            }
        }

        sA0 = sN0; sA1 = sN1;
        act = actn; actn = act2;
    }
}

// ---- fallback (insufficient scratch): direct fp32, slow but correct ----
__global__ __launch_bounds__(256) void meshconv_fallback(
    const float* __restrict__ x, const int* __restrict__ ge,
    const float* __restrict__ w, const float* __restrict__ bias,
    float* __restrict__ out) {
    __shared__ float f[5][32];
    __shared__ float G[5][32];
    __shared__ int idxs[4];
    const int e = blockIdx.x, b = blockIdx.y;
    const int tid = threadIdx.x;
    if (tid < 4) idxs[tid] = ge[((size_t)b * E_TOTAL + e) * 4 + tid];
    __syncthreads();
    if (tid < 160) {
        int k = tid >> 5, c = tid & 31;
        int src = (k == 0) ? e : idxs[k - 1];
        f[k][c] = x[((size_t)b * CIN + c) * E_TOTAL + src];
    }
    __syncthreads();
    if (tid < 32) {
        int c = tid;
        G[0][c] = f[0][c];
        G[1][c] = f[1][c] + f[3][c];
        G[2][c] = f[2][c] + f[4][c];
        G[3][c] = fabsf(f[1][c] - f[3][c]);
        G[4][c] = fabsf(f[2][c] - f[4][c]);
    }
    __syncthreads();
    if (tid < COUT) {
        float acc = bias[tid];
        for (int c = 0; c < CIN; c++)
#pragma unroll
            for (int g = 0; g < 5; g++)
                acc += G[g][c] * w[(tid * CIN + c) * 5 + g];
        out[((size_t)b * COUT + tid) * E_TOTAL + e] = acc;
    }
}

extern "C" void kernel_launch(void* const* d_in, const int* in_sizes, int n_in,
                              void* d_out, int out_size, void* d_ws, size_t ws_size,
                              hipStream_t stream) {
    const float* x = (const float*)d_in[0];
    const int* ge = (const int*)d_in[1];
    const float* w = (const float*)d_in[2];
    const float* bias = (const float*)d_in[3];
    float* out = (float*)d_out;

    const size_t xt_bytes = (size_t)B_TOTAL * E_TOTAL * CIN * 2;  // 51.2 MB
    const size_t need = 65536 + xt_bytes;
    if (ws_size < need) {
        dim3 grid(E_TOTAL, B_TOTAL);
        meshconv_fallback<<<grid, 256, 0, stream>>>(x, ge, w, bias, out);
        return;
    }
    unsigned short* wb = (unsigned short*)d_ws;
    unsigned short* xt = (unsigned short*)((char*)d_ws + 65536);

    prep_transpose<<<TILES * 8 + 1, 256, 0, stream>>>(x, (unsigned*)xt, w, wb);
    meshconv_main<<<NBLK * 8, 256, 0, stream>>>(xt, ge, (const u32x4*)wb, bias, out);
}

// Round 4
// 372.681 us; speedup vs baseline: 1.0362x; 1.0061x over previous
//
#include <hip/hip_runtime.h>
#include <stdint.h>

#define E_TOTAL 100000
#define B_TOTAL 8
#define CIN 32
#define COUT 64
#define TILES 1563   // ceil(E_TOTAL/64) for transpose
#define NUNITS 782   // ceil(E_TOTAL/128): one 128-e unit per block (4 waves x 32 e)

typedef float f32x4  __attribute__((ext_vector_type(4)));
typedef int   i32x4  __attribute__((ext_vector_type(4)));
typedef unsigned u32x4 __attribute__((ext_vector_type(4)));
typedef _Float16 h16x8 __attribute__((ext_vector_type(8)));

union HU { u32x4 u; h16x8 h; };

// fp32 pair -> packed fp16 pair (single v_cvt_pkrtz_f16_f32)
__device__ inline unsigned pkh(float lo, float hi) {
    auto r = __builtin_amdgcn_cvt_pkrtz(lo, hi);   // __fp16 ext_vector(2)
    return __builtin_bit_cast(unsigned, r);
}
__device__ inline h16x8 ash(u32x4 v) { HU x; x.u = v; return x.h; }
// |a - b| : 4x v_pk_sub_f16 + 4x v_and_b32
__device__ inline h16x8 habsd(h16x8 a, h16x8 b) {
    HU x; x.h = a - b;
#pragma unroll
    for (int i = 0; i < 4; i++) x.u[i] &= 0x7fff7fffu;
    return x.h;
}

// ---- kernel 1: fused weight-prep + x transpose/cast (fp16) ----
__global__ __launch_bounds__(256) void prep_transpose(
    const float* __restrict__ x, unsigned* __restrict__ xt,
    const float* __restrict__ w, unsigned short* __restrict__ wb) {
    const int tid = threadIdx.x;
    if (blockIdx.x >= TILES * 8) {
        for (int idx = tid; idx < 4 * 5 * 64 * 8; idx += 256) {
            int j = idx & 7;
            int lane = (idx >> 3) & 63;
            int tg = idx >> 9;
            int g = tg % 5;
            int t = tg / 5;
            int nn = lane & 15, qq = lane >> 4;
            int o = nn + 16 * t;
            int c = qq * 8 + j;
            _Float16 hv = (_Float16)w[(o * CIN + c) * 5 + g];   // RNE fp32->fp16
            wb[idx] = __builtin_bit_cast(unsigned short, hv);
        }
        return;
    }
    __shared__ float tbuf[CIN][65];
    const int b = blockIdx.x & 7;            // batch -> XCD affinity
    const int e0 = (blockIdx.x >> 3) * 64;
    const int el = tid & 63;
    const int cw = tid >> 6;
#pragma unroll
    for (int i = 0; i < 8; i++) {
        int c = cw * 8 + i;
        int e = e0 + el;
        float v = (e < E_TOTAL)
            ? __builtin_nontemporal_load(x + ((size_t)b * CIN + c) * E_TOTAL + e)
            : 0.f;
        tbuf[c][el] = v;
    }
    __syncthreads();
    const int c2 = tid & 15;
#pragma unroll
    for (int i = 0; i < 4; i++) {
        int el2 = (tid >> 4) * 4 + i;
        int e = e0 + el2;
        if (e < E_TOTAL) {
            xt[((size_t)b * E_TOTAL + e) * 16 + c2] =
                pkh(tbuf[c2 * 2][el2], tbuf[c2 * 2 + 1][el2]);
        }
    }
}

// ---- kernel 2: gather + symmetric functions + MFMA GEMM ----
// One 128-e unit per block, no loop, no software pipeline. Minimal per-wave
// register state (~110 VGPR) -> 4+ waves/SIMD; latency hiding comes from
// block-level TLP (6256 blocks, ~5 resident/CU with 20 KB LDS). Gathers are
// issued right after the barrier; the g=0 (self-row) MFMAs run under their
// latency.
__global__ __launch_bounds__(256) void meshconv_main(
    const unsigned short* __restrict__ xt,   // (B,E,32) fp16
    const int* __restrict__ ge,              // (B,E,4)
    const u32x4* __restrict__ wb,            // frag-ready fp16 weights (20 KB)
    const float* __restrict__ bias,          // (64)
    float* __restrict__ out) {               // (B,64,E) fp32
    __shared__ u32x4 wlds[1280];
    const int tid = threadIdx.x;
    const int lane = tid & 63;
    const int wv = tid >> 6;
    const int b = blockIdx.x & 7;            // batch -> XCD affinity
    const int unit = blockIdx.x >> 3;
    const int n = lane & 15;
    const int q = lane >> 4;
    const int co = q * 8;

    const unsigned short* xb = xt + (size_t)b * E_TOTAL * CIN;
    const int* geb = ge + (size_t)b * E_TOTAL * 4;

    const int e0 = unit * 128 + wv * 32;
    const bool act = e0 < E_TOTAL;           // E%32==0: full waves only

    // issue per-wave loads first (independent of the LDS weight staging)
    i32x4 nid0, nid1;
    u32x4 s0, s1;
    if (act) {
        nid0 = __builtin_nontemporal_load((const i32x4*)(geb + (size_t)(e0 + n) * 4));
        nid1 = __builtin_nontemporal_load((const i32x4*)(geb + (size_t)(e0 + 16 + n) * 4));
        s0 = *(const u32x4*)(xb + (size_t)(e0 + n) * CIN + co);
        s1 = *(const u32x4*)(xb + (size_t)(e0 + 16 + n) * CIN + co);
    }
    float bv[4];
#pragma unroll
    for (int t = 0; t < 4; t++) bv[t] = bias[n + 16 * t];

    // weight staging (L2-resident 20 KB, broadcast across blocks)
#pragma unroll
    for (int k = 0; k < 5; k++) wlds[tid + k * 256] = wb[tid + k * 256];
    __syncthreads();

    if (!act) return;

    // 8 independent random row-gathers, all in flight at once
    u32x4 g10, g20, g30, g40, g11, g21, g31, g41;
    g10 = *(const u32x4*)(xb + (size_t)nid0[0] * CIN + co);
    g20 = *(const u32x4*)(xb + (size_t)nid0[1] * CIN + co);
    g30 = *(const u32x4*)(xb + (size_t)nid0[2] * CIN + co);
    g40 = *(const u32x4*)(xb + (size_t)nid0[3] * CIN + co);
    g11 = *(const u32x4*)(xb + (size_t)nid1[0] * CIN + co);
    g21 = *(const u32x4*)(xb + (size_t)nid1[1] * CIN + co);
    g31 = *(const u32x4*)(xb + (size_t)nid1[2] * CIN + co);
    g41 = *(const u32x4*)(xb + (size_t)nid1[3] * CIN + co);

    f32x4 acc0[4], acc1[4];
#pragma unroll
    for (int t = 0; t < 4; t++)
#pragma unroll
        for (int r = 0; r < 4; r++) { acc0[t][r] = bv[t]; acc1[t][r] = bv[t]; }

    // ---- g = 0 (self rows): runs while gathers are in flight ----
    {
        HU av0; av0.u = s0;
        HU av1; av1.u = s1;
#pragma unroll
        for (int t = 0; t < 4; t++) {
            HU bw; bw.u = wlds[(t * 5 + 0) * 64 + lane];
            acc0[t] = __builtin_amdgcn_mfma_f32_16x16x32_f16(av0.h, bw.h, acc0[t], 0, 0, 0);
            acc1[t] = __builtin_amdgcn_mfma_f32_16x16x32_f16(av1.h, bw.h, acc1[t], 0, 0, 0);
        }
    }
    // ---- pair (g1, g3): sum + absdiff of neighbors 1,3 ----
    {
        h16x8 p0 = ash(g10) + ash(g30);
        h16x8 p1 = ash(g11) + ash(g31);
        h16x8 m0 = habsd(ash(g10), ash(g30));
        h16x8 m1 = habsd(ash(g11), ash(g31));
#pragma unroll
        for (int t = 0; t < 4; t++) {
            HU bw; bw.u = wlds[(t * 5 + 1) * 64 + lane];
            acc0[t] = __builtin_amdgcn_mfma_f32_16x16x32_f16(p0, bw.h, acc0[t], 0, 0, 0);
            acc1[t] = __builtin_amdgcn_mfma_f32_16x16x32_f16(p1, bw.h, acc1[t], 0, 0, 0);
        }
#pragma unroll
        for (int t = 0; t < 4; t++) {
            HU bw; bw.u = wlds[(t * 5 + 3) * 64 + lane];
            acc0[t] = __builtin_amdgcn_mfma_f32_16x16x32_f16(m0, bw.h, acc0[t], 0, 0, 0);
            acc1[t] = __builtin_amdgcn_mfma_f32_16x16x32_f16(m1, bw.h, acc1[t], 0, 0, 0);
        }
    }
    // ---- pair (g2, g4): sum + absdiff of neighbors 2,4 ----
    {
        h16x8 p0 = ash(g20) + ash(g40);
        h16x8 p1 = ash(g21) + ash(g41);
        h16x8 m0 = habsd(ash(g20), ash(g40));
        h16x8 m1 = habsd(ash(g21), ash(g41));
#pragma unroll
        for (int t = 0; t < 4; t++) {
            HU bw; bw.u = wlds[(t * 5 + 2) * 64 + lane];
            acc0[t] = __builtin_amdgcn_mfma_f32_16x16x32_f16(p0, bw.h, acc0[t], 0, 0, 0);
            acc1[t] = __builtin_amdgcn_mfma_f32_16x16x32_f16(p1, bw.h, acc1[t], 0, 0, 0);
        }
#pragma unroll
        for (int t = 0; t < 4; t++) {
            HU bw; bw.u = wlds[(t * 5 + 4) * 64 + lane];
            acc0[t] = __builtin_amdgcn_mfma_f32_16x16x32_f16(m0, bw.h, acc0[t], 0, 0, 0);
            acc1[t] = __builtin_amdgcn_mfma_f32_16x16x32_f16(m1, bw.h, acc1[t], 0, 0, 0);
        }
    }

    // per o-row: two adjacent f32x4 stores -> 128 B contiguous per wave
#pragma unroll
    for (int t = 0; t < 4; t++) {
        const int o = n + 16 * t;
        float* orow = out + ((size_t)b * COUT + o) * E_TOTAL + e0 + q * 4;
        __builtin_nontemporal_store(acc0[t], (f32x4*)orow);
        __builtin_nontemporal_store(acc1[t], (f32x4*)(orow + 16));
    }
}

// ---- fallback (insufficient scratch): direct fp32, slow but correct ----
__global__ __launch_bounds__(256) void meshconv_fallback(
    const float* __restrict__ x, const int* __restrict__ ge,
    const float* __restrict__ w, const float* __restrict__ bias,
    float* __restrict__ out) {
    __shared__ float f[5][32];
    __shared__ float G[5][32];
    __shared__ int idxs[4];
    const int e = blockIdx.x, b = blockIdx.y;
    const int tid = threadIdx.x;
    if (tid < 4) idxs[tid] = ge[((size_t)b * E_TOTAL + e) * 4 + tid];
    __syncthreads();
    if (tid < 160) {
        int k = tid >> 5, c = tid & 31;
        int src = (k == 0) ? e : idxs[k - 1];
        f[k][c] = x[((size_t)b * CIN + c) * E_TOTAL + src];
    }
    __syncthreads();
    if (tid < 32) {
        int c = tid;
        G[0][c] = f[0][c];
        G[1][c] = f[1][c] + f[3][c];
        G[2][c] = f[2][c] + f[4][c];
        G[3][c] = fabsf(f[1][c] - f[3][c]);
        G[4][c] = fabsf(f[2][c] - f[4][c]);
    }
    __syncthreads();
    if (tid < COUT) {
        float acc = bias[tid];
        for (int c = 0; c < CIN; c++)
#pragma unroll
            for (int g = 0; g < 5; g++)
                acc += G[g][c] * w[(tid * CIN + c) * 5 + g];
        out[((size_t)b * COUT + tid) * E_TOTAL + e] = acc;
    }
}

extern "C" void kernel_launch(void* const* d_in, const int* in_sizes, int n_in,
                              void* d_out, int out_size, void* d_ws, size_t ws_size,
                              hipStream_t stream) {
    const float* x = (const float*)d_in[0];
    const int* ge = (const int*)d_in[1];
    const float* w = (const float*)d_in[2];
    const float* bias = (const float*)d_in[3];
    float* out = (float*)d_out;

    const size_t xt_bytes = (size_t)B_TOTAL * E_TOTAL * CIN * 2;  // 51.2 MB
    const size_t need = 65536 + xt_bytes;
    if (ws_size < need) {
        dim3 grid(E_TOTAL, B_TOTAL);
        meshconv_fallback<<<grid, 256, 0, stream>>>(x, ge, w, bias, out);
        return;
    }
    unsigned short* wb = (unsigned short*)d_ws;
    unsigned short* xt = (unsigned short*)((char*)d_ws + 65536);

    prep_transpose<<<TILES * 8 + 1, 256, 0, stream>>>(x, (unsigned*)xt, w, wb);
    meshconv_main<<<NUNITS * 8, 256, 0, stream>>>(xt, ge, (const u32x4*)wb, bias, out);
}